// Round 3
// baseline (8134.156 us; speedup 1.0000x reference)
//
#include <hip/hip_runtime.h>
#include <math.h>

#define DIM_    256
#define DSTATE_ 64
#define DINNER_ 512
#define DTRANK_ 16
#define NSEQ_   8192
#define BSZ_    8

__device__ __forceinline__ float silu_(float v)     { return v / (1.f + __expf(-v)); }
__device__ __forceinline__ float softplus_(float v) { return (v > 20.f) ? v : log1pf(__expf(v)); }

// global row for chunk-local row r: b = r>>lgL, nl = r&(L-1); g = b*8192 + n0 + nl
__device__ __forceinline__ size_t grow_(int r, int n0, int lgL) {
  int L1 = (1 << lgL) - 1;
  return (size_t)(r >> lgL) * NSEQ_ + n0 + (r & L1);
}

// ---------------- LayerNorm: one wave per chunk-local row ----------------
__global__ void ln_kernel(const float* __restrict__ x, const float* __restrict__ g,
                          const float* __restrict__ bb, float* __restrict__ xn,
                          int Rc, int n0, int lgL) {
  int wave = threadIdx.x >> 6, lane = threadIdx.x & 63;
  int row = blockIdx.x * 4 + wave;
  if (row >= Rc) return;
  const float4* xr = (const float4*)(x + grow_(row, n0, lgL) * DIM_);
  float4 v = xr[lane];
  float s = v.x + v.y + v.z + v.w;
#pragma unroll
  for (int o = 32; o; o >>= 1) s += __shfl_xor(s, o, 64);
  float mu = s * (1.f / DIM_);
  float ax = v.x - mu, ay = v.y - mu, az = v.z - mu, aw = v.w - mu;
  float q = ax * ax + ay * ay + az * az + aw * aw;
#pragma unroll
  for (int o = 32; o; o >>= 1) q += __shfl_xor(q, o, 64);
  float rs = rsqrtf(q * (1.f / DIM_) + 1e-5f);
  float4 gv = ((const float4*)g)[lane];
  float4 bv = ((const float4*)bb)[lane];
  float4 o4;
  o4.x = ax * rs * gv.x + bv.x;
  o4.y = ay * rs * gv.y + bv.y;
  o4.z = az * rs * gv.z + bv.z;
  o4.w = aw * rs * gv.w + bv.w;
  ((float4*)(xn + (size_t)row * DIM_))[lane] = o4;
}

// ---------------- Tiled f32 GEMM: C = A(McxK) @ B(KxN) ----------------
// 64x64 tile, BK=16, 256 threads, 4x4 micro-tile.
// MODE 1: N==1024 split: col<512 -> C0 (xi), col>=512 -> C1 = silu(v)
// MODE 2: store to C0 at global row mapping (chunked out write)
template <int MODE>
__global__ void gemm_kernel(const float* __restrict__ A, const float* __restrict__ B,
                            float* __restrict__ C0, float* __restrict__ C1,
                            int M, int N, int K, int n0, int lgL) {
  __shared__ float As[16][64];
  __shared__ float Bs[16][64];
  int tid = threadIdx.x;
  int m0 = blockIdx.y * 64;
  int nb0 = blockIdx.x * 64;
  int ty = tid >> 4, tx = tid & 15;

  int am = tid >> 2;
  int ak = (tid & 3) * 4;
  int bk = tid >> 4;
  int bn = (tid & 15) * 4;

  float acc[4][4];
#pragma unroll
  for (int i = 0; i < 4; i++)
#pragma unroll
    for (int j = 0; j < 4; j++) acc[i][j] = 0.f;

  for (int k0 = 0; k0 < K; k0 += 16) {
    float4 av = *(const float4*)(A + (size_t)(m0 + am) * K + k0 + ak);
    As[ak + 0][am] = av.x;
    As[ak + 1][am] = av.y;
    As[ak + 2][am] = av.z;
    As[ak + 3][am] = av.w;
    *(float4*)&Bs[bk][bn] = *(const float4*)(B + (size_t)(k0 + bk) * N + nb0 + bn);
    __syncthreads();
#pragma unroll
    for (int kk = 0; kk < 16; kk++) {
      float4 a = *(float4*)&As[kk][ty * 4];
      float4 b = *(float4*)&Bs[kk][tx * 4];
      float ar[4] = {a.x, a.y, a.z, a.w};
      float br[4] = {b.x, b.y, b.z, b.w};
#pragma unroll
      for (int i = 0; i < 4; i++)
#pragma unroll
        for (int j = 0; j < 4; j++) acc[i][j] = fmaf(ar[i], br[j], acc[i][j]);
    }
    __syncthreads();
  }

#pragma unroll
  for (int i = 0; i < 4; i++) {
    int row = m0 + ty * 4 + i;
    int col = nb0 + tx * 4;
    float4 o4 = {acc[i][0], acc[i][1], acc[i][2], acc[i][3]};
    if (MODE == 1) {
      if (col < DINNER_) {
        *(float4*)(C0 + (size_t)row * DINNER_ + col) = o4;
      } else {
        o4.x = silu_(o4.x); o4.y = silu_(o4.y); o4.z = silu_(o4.z); o4.w = silu_(o4.w);
        *(float4*)(C1 + (size_t)row * DINNER_ + (col - DINNER_)) = o4;
      }
    } else {
      *(float4*)(C0 + grow_(row, n0, lgL) * DIM_ + col) = o4;
    }
  }
}

// ---------------- Depthwise causal conv (k=4) + bias + SiLU, with chunk carry ----------------
__global__ void conv_silu_kernel(const float* __restrict__ xi, const float* __restrict__ w,
                                 const float* __restrict__ cb, float* __restrict__ xc,
                                 const float* __restrict__ xiC, int Rc, int first, int lgL) {
  int idx = blockIdx.x * 256 + threadIdx.x;  // over Rc*512
  if (idx >= Rc * DINNER_) return;
  int d = idx & (DINNER_ - 1);
  int r = idx >> 9;                // chunk-local row
  int nl = r & ((1 << lgL) - 1);   // position within chunk
  int b = r >> lgL;
  float acc = cb[d];
#pragma unroll
  for (int k = 0; k < 4; k++) {
    int p = nl - 3 + k;
    float xv;
    if (p >= 0) xv = xi[(size_t)(r - 3 + k) * DINNER_ + d];
    else if (first) xv = 0.f;
    else xv = xiC[(size_t)(b * 3 + (3 + p)) * DINNER_ + d];
    acc = fmaf(w[d * 4 + k], xv, acc);
  }
  xc[idx] = acc * (1.f / (1.f + __expf(-acc)));
}

// ---------------- save last-3 xi rows per batch into carry ----------------
__global__ void save_carry_kernel(const float* __restrict__ xi, float* __restrict__ xiC, int L) {
  int t = blockIdx.x * 256 + threadIdx.x;  // 8*3*512 = 12288
  if (t >= BSZ_ * 3 * DINNER_) return;
  int d = t & (DINNER_ - 1);
  int rem = t >> 9;        // b*3 + row
  int b = rem / 3, row = rem - b * 3;
  xiC[t] = xi[(size_t)(b * L + L - 3 + row) * DINNER_ + d];
}

// ---------------- x-proj (512->80) + dt-proj (16->512) + softplus, per row ----------------
__global__ void xproj_kernel(const float* __restrict__ xc, const float* __restrict__ Wx,
                             const float* __restrict__ Wdt, const float* __restrict__ bdt,
                             float* __restrict__ dt, float* __restrict__ Bm, int Rc) {
  __shared__ float xr[DINNER_];
  __shared__ float dtr[DTRANK_];
  int row = blockIdx.x;
  int t = threadIdx.x;
  *(float2*)&xr[t * 2] = *(const float2*)(xc + (size_t)row * DINNER_ + t * 2);
  __syncthreads();
  if (t < 80) {
    float a = 0.f;
#pragma unroll 8
    for (int k = 0; k < DINNER_; k++) a = fmaf(xr[k], Wx[k * 80 + t], a);
    if (t < DTRANK_) dtr[t] = a;
    else Bm[(size_t)row * DSTATE_ + (t - DTRANK_)] = a;
  }
  __syncthreads();
#pragma unroll
  for (int rep = 0; rep < 2; rep++) {
    int j = t + rep * 256;
    float a = bdt[j];
#pragma unroll
    for (int r = 0; r < DTRANK_; r++) a = fmaf(dtr[r], Wdt[r * DINNER_ + j], a);
    dt[(size_t)row * DINNER_ + j] = softplus_(a);
  }
}

// ---------------- Cm = C_SA @ W_C: 4 chunk-local rows per block ----------------
__global__ void cm_kernel(const float* __restrict__ Csa, const float* __restrict__ Wc,
                          float* __restrict__ Cm, int Rc, int n0, int lgL) {
  __shared__ float cr[4 * DIM_];
  int t = threadIdx.x;
  int row0 = blockIdx.x * 4;
  int lr = t >> 6;  // which of the 4 rows this thread's float4 belongs to
  // load 4 rows (each 256 floats = 64 float4); thread t loads float4 #t
  ((float4*)cr)[t] = ((const float4*)(Csa + grow_(row0 + lr, n0, lgL) * DIM_))[t & 63];
  __syncthreads();
  int r = t >> 6, s = t & 63;
  float a = 0.f;
#pragma unroll 8
  for (int k = 0; k < DIM_; k++) a = fmaf(cr[r * DIM_ + k], Wc[k * DSTATE_ + s], a);
  Cm[(size_t)(row0 + r) * DSTATE_ + s] = a;
}

// ---------------- Selective scan over one chunk; h carried in hC ----------------
// y written IN PLACE over sz.
__global__ void scan_kernel(const float* __restrict__ dt, const float* __restrict__ Bm,
                            const float* __restrict__ Cm, const float* __restrict__ xc,
                            float* __restrict__ szy, const float* __restrict__ Alog,
                            const float* __restrict__ Dp, float* __restrict__ hC,
                            int L, int first) {
  int wave = threadIdx.x >> 6, lane = threadIdx.x & 63;
  int gd = blockIdx.x * 4 + wave;  // over 8*512
  int b = gd >> 9;
  int d = gd & (DINNER_ - 1);
  float Av = -__expf(Alog[d * DSTATE_ + lane]);
  float Dd = Dp[d];
  float h = first ? 0.f : hC[(size_t)gd * DSTATE_ + lane];
  size_t rbase = (size_t)b * L;
  const float* dtp = dt + rbase * DINNER_ + d;
  const float* xcp = xc + rbase * DINNER_ + d;
  float* szp      = szy + rbase * DINNER_ + d;
  const float* Bp  = Bm + rbase * DSTATE_ + lane;
  const float* Cp  = Cm + rbase * DSTATE_ + lane;

  for (int n = 0; n < L; n++) {
    float dtv = dtp[(size_t)n * DINNER_];
    float xcv = xcp[(size_t)n * DINNER_];
    float Bv  = Bp[(size_t)n * DSTATE_];
    float Cv  = Cp[(size_t)n * DSTATE_];
    float a = __expf(dtv * Av);
    h = fmaf(a, h, dtv * xcv * Bv);
    float p = h * Cv;
#pragma unroll
    for (int o = 32; o; o >>= 1) p += __shfl_xor(p, o, 64);
    if (lane == 0) {
      float szv = szp[(size_t)n * DINNER_];
      szp[(size_t)n * DINNER_] = (p + xcv * Dd) * szv;
    }
  }
  hC[(size_t)gd * DSTATE_ + lane] = h;
}

extern "C" void kernel_launch(void* const* d_in, const int* in_sizes, int n_in,
                              void* d_out, int out_size, void* d_ws, size_t ws_size,
                              hipStream_t stream) {
  const float* x      = (const float*)d_in[0];
  const float* C_SA   = (const float*)d_in[1];
  const float* ln_g   = (const float*)d_in[2];
  const float* ln_b   = (const float*)d_in[3];
  const float* W_in   = (const float*)d_in[4];
  const float* conv_w = (const float*)d_in[5];
  const float* conv_b = (const float*)d_in[6];
  const float* W_xp   = (const float*)d_in[7];
  const float* W_dt   = (const float*)d_in[8];
  const float* b_dt   = (const float*)d_in[9];
  const float* W_C    = (const float*)d_in[10];
  const float* A_log  = (const float*)d_in[11];
  const float* Dp     = (const float*)d_in[12];
  const float* W_out  = (const float*)d_in[13];
  float* out = (float*)d_out;

  // choose chunk length L (power of 2) from ws_size; cap 2048 (keeps chunk in L3)
  int L = 2048;
  while (L > 64) {
    size_t need = (size_t)BSZ_ * L * 1920 * 4 + (size_t)(BSZ_ * 3 * DINNER_) * 4
                + (size_t)(BSZ_ * DINNER_ * DSTATE_) * 4 + 4096;
    if (need <= ws_size) break;
    L >>= 1;
  }
  int lgL = __builtin_ctz(L);
  int Rc = BSZ_ * L;
  int nchunks = NSEQ_ / L;

  float* ws = (float*)d_ws;
  float* xn  = ws;                          // Rc*256
  float* xi  = xn + (size_t)Rc * DIM_;      // Rc*512   (dt aliases after conv)
  float* sz  = xi + (size_t)Rc * DINNER_;   // Rc*512   (y in place)
  float* xc  = sz + (size_t)Rc * DINNER_;   // Rc*512
  float* Bm  = xc + (size_t)Rc * DINNER_;   // Rc*64
  float* Cm  = Bm + (size_t)Rc * DSTATE_;   // Rc*64
  float* xiC = Cm + (size_t)Rc * DSTATE_;   // 8*3*512
  float* hC  = xiC + BSZ_ * 3 * DINNER_;    // 8*512*64
  float* dtb = xi;

  for (int c = 0; c < nchunks; c++) {
    int n0 = c * L;
    int first = (c == 0) ? 1 : 0;
    ln_kernel<<<Rc / 4, 256, 0, stream>>>(x, ln_g, ln_b, xn, Rc, n0, lgL);
    gemm_kernel<1><<<dim3(1024 / 64, Rc / 64), 256, 0, stream>>>(xn, W_in, xi, sz, Rc, 1024, DIM_, 0, 0);
    conv_silu_kernel<<<(Rc * DINNER_) / 256, 256, 0, stream>>>(xi, conv_w, conv_b, xc, xiC, Rc, first, lgL);
    save_carry_kernel<<<48, 256, 0, stream>>>(xi, xiC, L);
    xproj_kernel<<<Rc, 256, 0, stream>>>(xc, W_xp, W_dt, b_dt, dtb, Bm, Rc);
    cm_kernel<<<Rc / 4, 256, 0, stream>>>(C_SA, W_C, Cm, Rc, n0, lgL);
    scan_kernel<<<(BSZ_ * DINNER_) / 4, 256, 0, stream>>>(dtb, Bm, Cm, xc, sz, A_log, Dp, hC, L, first);
    gemm_kernel<2><<<dim3(DIM_ / 64, Rc / 64), 256, 0, stream>>>(sz, W_out, out, nullptr, Rc, DIM_, DINNER_, n0, lgL);
  }
}

// Round 4
// 4646.746 us; speedup vs baseline: 1.7505x; 1.7505x over previous
//
#include <hip/hip_runtime.h>
#include <math.h>

#define DIM_    256
#define DSTATE_ 64
#define DINNER_ 512
#define DTRANK_ 16
#define NSEQ_   8192
#define BSZ_    8
#define STILE_  32

__device__ __forceinline__ float silu_(float v)     { return v / (1.f + __expf(-v)); }
__device__ __forceinline__ float softplus_(float v) { return (v > 20.f) ? v : log1pf(__expf(v)); }

// global row for chunk-local row r: b = r>>lgL, nl = r&(L-1); g = b*8192 + n0 + nl
__device__ __forceinline__ size_t grow_(int r, int n0, int lgL) {
  int L1 = (1 << lgL) - 1;
  return (size_t)(r >> lgL) * NSEQ_ + n0 + (r & L1);
}

// ---------------- LayerNorm: one wave per chunk-local row ----------------
__global__ void ln_kernel(const float* __restrict__ x, const float* __restrict__ g,
                          const float* __restrict__ bb, float* __restrict__ xn,
                          int Rc, int n0, int lgL) {
  int wave = threadIdx.x >> 6, lane = threadIdx.x & 63;
  int row = blockIdx.x * 4 + wave;
  if (row >= Rc) return;
  const float4* xr = (const float4*)(x + grow_(row, n0, lgL) * DIM_);
  float4 v = xr[lane];
  float s = v.x + v.y + v.z + v.w;
#pragma unroll
  for (int o = 32; o; o >>= 1) s += __shfl_xor(s, o, 64);
  float mu = s * (1.f / DIM_);
  float ax = v.x - mu, ay = v.y - mu, az = v.z - mu, aw = v.w - mu;
  float q = ax * ax + ay * ay + az * az + aw * aw;
#pragma unroll
  for (int o = 32; o; o >>= 1) q += __shfl_xor(q, o, 64);
  float rs = rsqrtf(q * (1.f / DIM_) + 1e-5f);
  float4 gv = ((const float4*)g)[lane];
  float4 bv = ((const float4*)bb)[lane];
  float4 o4;
  o4.x = ax * rs * gv.x + bv.x;
  o4.y = ay * rs * gv.y + bv.y;
  o4.z = az * rs * gv.z + bv.z;
  o4.w = aw * rs * gv.w + bv.w;
  ((float4*)(xn + (size_t)row * DIM_))[lane] = o4;
}

// ---------------- Tiled f32 GEMM: C = A(McxK) @ B(KxN) ----------------
// 64x64 tile, BK=16, 256 threads, 4x4 micro-tile.
// MODE 1: A row-major [M][K]; N==1024 split: col<512 -> C0 (xi), col>=512 -> C1 = silu
// MODE 2: A TRANSPOSED, stored [b][K][L] (yT); store C0 at global row mapping
template <int MODE>
__global__ void gemm_kernel(const float* __restrict__ A, const float* __restrict__ B,
                            float* __restrict__ C0, float* __restrict__ C1,
                            int M, int N, int K, int n0, int lgL, int Lp) {
  __shared__ float As[16][64];
  __shared__ float Bs[16][64];
  int tid = threadIdx.x;
  int m0 = blockIdx.y * 64;
  int nb0 = blockIdx.x * 64;
  int ty = tid >> 4, tx = tid & 15;

  int am = tid >> 2;
  int ak = (tid & 3) * 4;
  int bk = tid >> 4;
  int bn = (tid & 15) * 4;

  float acc[4][4];
#pragma unroll
  for (int i = 0; i < 4; i++)
#pragma unroll
    for (int j = 0; j < 4; j++) acc[i][j] = 0.f;

  for (int k0 = 0; k0 < K; k0 += 16) {
    if (MODE == 1) {
      float4 av = *(const float4*)(A + (size_t)(m0 + am) * K + k0 + ak);
      As[ak + 0][am] = av.x;
      As[ak + 1][am] = av.y;
      As[ak + 2][am] = av.z;
      As[ak + 3][am] = av.w;
    } else {
      // A^T: [b][K][Lp]; tile rows m0..m0+63 all in same b (Lp multiple of 64)
      int bb = m0 >> lgL;
      int nl0 = m0 & ((1 << lgL) - 1);
      int kk = tid >> 4;           // 0..15
      int mm = (tid & 15) * 4;     // 0..60
      float4 av = *(const float4*)(A + ((size_t)bb * DINNER_ + k0 + kk) * Lp + nl0 + mm);
      *(float4*)&As[kk][mm] = av;
    }
    *(float4*)&Bs[bk][bn] = *(const float4*)(B + (size_t)(k0 + bk) * N + nb0 + bn);
    __syncthreads();
#pragma unroll
    for (int kk = 0; kk < 16; kk++) {
      float4 a = *(float4*)&As[kk][ty * 4];
      float4 b = *(float4*)&Bs[kk][tx * 4];
      float ar[4] = {a.x, a.y, a.z, a.w};
      float br[4] = {b.x, b.y, b.z, b.w};
#pragma unroll
      for (int i = 0; i < 4; i++)
#pragma unroll
        for (int j = 0; j < 4; j++) acc[i][j] = fmaf(ar[i], br[j], acc[i][j]);
    }
    __syncthreads();
  }

#pragma unroll
  for (int i = 0; i < 4; i++) {
    int row = m0 + ty * 4 + i;
    int col = nb0 + tx * 4;
    float4 o4 = {acc[i][0], acc[i][1], acc[i][2], acc[i][3]};
    if (MODE == 1) {
      if (col < DINNER_) {
        *(float4*)(C0 + (size_t)row * DINNER_ + col) = o4;
      } else {
        o4.x = silu_(o4.x); o4.y = silu_(o4.y); o4.z = silu_(o4.z); o4.w = silu_(o4.w);
        *(float4*)(C1 + (size_t)row * DINNER_ + (col - DINNER_)) = o4;
      }
    } else {
      *(float4*)(C0 + grow_(row, n0, lgL) * DIM_ + col) = o4;
    }
  }
}

// ---------------- Depthwise causal conv (k=4) + bias + SiLU, with chunk carry ----------------
__global__ void conv_silu_kernel(const float* __restrict__ xi, const float* __restrict__ w,
                                 const float* __restrict__ cb, float* __restrict__ xc,
                                 const float* __restrict__ xiC, int Rc, int first, int lgL) {
  int idx = blockIdx.x * 256 + threadIdx.x;  // over Rc*512
  if (idx >= Rc * DINNER_) return;
  int d = idx & (DINNER_ - 1);
  int r = idx >> 9;
  int nl = r & ((1 << lgL) - 1);
  int b = r >> lgL;
  float acc = cb[d];
#pragma unroll
  for (int k = 0; k < 4; k++) {
    int p = nl - 3 + k;
    float xv;
    if (p >= 0) xv = xi[(size_t)(r - 3 + k) * DINNER_ + d];
    else if (first) xv = 0.f;
    else xv = xiC[(size_t)(b * 3 + (3 + p)) * DINNER_ + d];
    acc = fmaf(w[d * 4 + k], xv, acc);
  }
  xc[idx] = acc * (1.f / (1.f + __expf(-acc)));
}

// ---------------- save last-3 xi rows per batch into carry ----------------
__global__ void save_carry_kernel(const float* __restrict__ xi, float* __restrict__ xiC, int L) {
  int t = blockIdx.x * 256 + threadIdx.x;
  if (t >= BSZ_ * 3 * DINNER_) return;
  int d = t & (DINNER_ - 1);
  int rem = t >> 9;
  int b = rem / 3, row = rem - b * 3;
  xiC[t] = xi[(size_t)(b * L + L - 3 + row) * DINNER_ + d];
}

// ---------------- x-proj (512->80) + dt-proj (16->512) + softplus, per row ----------------
__global__ void xproj_kernel(const float* __restrict__ xc, const float* __restrict__ Wx,
                             const float* __restrict__ Wdt, const float* __restrict__ bdt,
                             float* __restrict__ dt, float* __restrict__ Bm, int Rc) {
  __shared__ float xr[DINNER_];
  __shared__ float dtr[DTRANK_];
  int row = blockIdx.x;
  int t = threadIdx.x;
  *(float2*)&xr[t * 2] = *(const float2*)(xc + (size_t)row * DINNER_ + t * 2);
  __syncthreads();
  if (t < 80) {
    float a = 0.f;
#pragma unroll 8
    for (int k = 0; k < DINNER_; k++) a = fmaf(xr[k], Wx[k * 80 + t], a);
    if (t < DTRANK_) dtr[t] = a;
    else Bm[(size_t)row * DSTATE_ + (t - DTRANK_)] = a;
  }
  __syncthreads();
#pragma unroll
  for (int rep = 0; rep < 2; rep++) {
    int j = t + rep * 256;
    float a = bdt[j];
#pragma unroll
    for (int r = 0; r < DTRANK_; r++) a = fmaf(dtr[r], Wdt[r * DINNER_ + j], a);
    dt[(size_t)row * DINNER_ + j] = softplus_(a);
  }
}

// ---------------- Cm = C_SA @ W_C: 4 chunk-local rows per block ----------------
__global__ void cm_kernel(const float* __restrict__ Csa, const float* __restrict__ Wc,
                          float* __restrict__ Cm, int Rc, int n0, int lgL) {
  __shared__ float cr[4 * DIM_];
  int t = threadIdx.x;
  int row0 = blockIdx.x * 4;
  int lr = t >> 6;
  ((float4*)cr)[t] = ((const float4*)(Csa + grow_(row0 + lr, n0, lgL) * DIM_))[t & 63];
  __syncthreads();
  int r = t >> 6, s = t & 63;
  float a = 0.f;
#pragma unroll 8
  for (int k = 0; k < DIM_; k++) a = fmaf(cr[r * DIM_ + k], Wc[k * DSTATE_ + s], a);
  Cm[(size_t)(row0 + r) * DSTATE_ + s] = a;
}

// ---------------- 3-tensor transpose: [b][L][512] -> [b][512][L] ----------------
__global__ void transpose3_kernel(const float* __restrict__ dt, const float* __restrict__ xc,
                                  const float* __restrict__ sz, float* __restrict__ dtT,
                                  float* __restrict__ xcT, float* __restrict__ szT, int L) {
  __shared__ float tile[64][65];
  int z = blockIdx.z;
  int which = z >> 3, b = z & 7;   // z = which*8 + b
  const float* in = (which == 0) ? dt : (which == 1) ? xc : sz;
  float* outp     = (which == 0) ? dtT : (which == 1) ? xcT : szT;
  int nt0 = blockIdx.x * 64, d0 = blockIdx.y * 64;
  int tx = threadIdx.x & 63, ty4 = threadIdx.x >> 6;
#pragma unroll 4
  for (int r = ty4; r < 64; r += 4)
    tile[r][tx] = in[((size_t)b * L + nt0 + r) * DINNER_ + d0 + tx];
  __syncthreads();
#pragma unroll 4
  for (int r = ty4; r < 64; r += 4)
    outp[((size_t)b * DINNER_ + d0 + r) * L + nt0 + tx] = tile[tx][r];
}

// ---------------- Selective scan: wave=(b,d), lane=s; dt/xc/sz in [b][d][n] ----------------
// 4-step unroll; B/C tiles staged in LDS (shared by 4 waves of same b).
// y written IN PLACE over szT.
__global__ void scan_kernel(const float* __restrict__ dtT, const float* __restrict__ Bm,
                            const float* __restrict__ Cm, const float* __restrict__ xcT,
                            float* __restrict__ szyT, const float* __restrict__ Alog,
                            const float* __restrict__ Dp, float* __restrict__ hC,
                            int L, int first) {
  __shared__ float BsS[STILE_ * 64];
  __shared__ float CsS[STILE_ * 64];
  int wave = threadIdx.x >> 6, lane = threadIdx.x & 63;
  int gd = blockIdx.x * 4 + wave;  // (b, d..d+3) same b
  int b = gd >> 9;
  int d = gd & (DINNER_ - 1);
  float Av = -__expf(Alog[d * DSTATE_ + lane]);
  float Dd = Dp[d];
  float h = first ? 0.f : hC[(size_t)gd * DSTATE_ + lane];
  const float* dtp = dtT + (size_t)gd * L;
  const float* xcp = xcT + (size_t)gd * L;
  float* szp = szyT + (size_t)gd * L;
  const float* Bb = Bm + (size_t)b * L * DSTATE_;
  const float* Cb = Cm + (size_t)b * L * DSTATE_;

  for (int t0 = 0; t0 < L; t0 += STILE_) {
    __syncthreads();
    {
      const float4* srcB = (const float4*)(Bb + (size_t)t0 * DSTATE_);
      const float4* srcC = (const float4*)(Cb + (size_t)t0 * DSTATE_);
      float4* dstB = (float4*)BsS;
      float4* dstC = (float4*)CsS;
      dstB[threadIdx.x]       = srcB[threadIdx.x];
      dstB[threadIdx.x + 256] = srcB[threadIdx.x + 256];
      dstC[threadIdx.x]       = srcC[threadIdx.x];
      dstC[threadIdx.x + 256] = srcC[threadIdx.x + 256];
    }
    __syncthreads();
#pragma unroll
    for (int tt = 0; tt < STILE_; tt += 4) {
      int n = t0 + tt;
      float4 dt4 = *(const float4*)(dtp + n);
      float4 xc4 = *(const float4*)(xcp + n);
      float dtk[4] = {dt4.x, dt4.y, dt4.z, dt4.w};
      float xck[4] = {xc4.x, xc4.y, xc4.z, xc4.w};
      float p[4];
#pragma unroll
      for (int k = 0; k < 4; k++) {
        float a = __expf(dtk[k] * Av);
        float Bv = BsS[(tt + k) * 64 + lane];
        h = fmaf(a, h, dtk[k] * xck[k] * Bv);
        p[k] = h * CsS[(tt + k) * 64 + lane];
      }
#pragma unroll
      for (int o = 32; o; o >>= 1) {
#pragma unroll
        for (int k = 0; k < 4; k++) p[k] += __shfl_xor(p[k], o, 64);
      }
      if (lane == 0) {
        float4 sz4 = *(const float4*)(szp + n);
        float4 y4;
        y4.x = (p[0] + xck[0] * Dd) * sz4.x;
        y4.y = (p[1] + xck[1] * Dd) * sz4.y;
        y4.z = (p[2] + xck[2] * Dd) * sz4.z;
        y4.w = (p[3] + xck[3] * Dd) * sz4.w;
        *(float4*)(szp + n) = y4;
      }
    }
  }
  hC[(size_t)gd * DSTATE_ + lane] = h;
}

extern "C" void kernel_launch(void* const* d_in, const int* in_sizes, int n_in,
                              void* d_out, int out_size, void* d_ws, size_t ws_size,
                              hipStream_t stream) {
  const float* x      = (const float*)d_in[0];
  const float* C_SA   = (const float*)d_in[1];
  const float* ln_g   = (const float*)d_in[2];
  const float* ln_b   = (const float*)d_in[3];
  const float* W_in   = (const float*)d_in[4];
  const float* conv_w = (const float*)d_in[5];
  const float* conv_b = (const float*)d_in[6];
  const float* W_xp   = (const float*)d_in[7];
  const float* W_dt   = (const float*)d_in[8];
  const float* b_dt   = (const float*)d_in[9];
  const float* W_C    = (const float*)d_in[10];
  const float* A_log  = (const float*)d_in[11];
  const float* Dp     = (const float*)d_in[12];
  const float* W_out  = (const float*)d_in[13];
  float* out = (float*)d_out;

  // choose chunk length L (power of 2, >=64) from ws_size; cap 2048
  int L = 2048;
  while (L > 64) {
    size_t need = (size_t)BSZ_ * L * 3456 * 4 + (size_t)274432 * 4 + 4096;
    if (need <= ws_size) break;
    L >>= 1;
  }
  int lgL = __builtin_ctz(L);
  int Rc = BSZ_ * L;
  int nchunks = NSEQ_ / L;

  float* ws = (float*)d_ws;
  float* xn  = ws;                          // Rc*256
  float* xi  = xn + (size_t)Rc * DIM_;      // Rc*512 (dt aliases after conv)
  float* sz  = xi + (size_t)Rc * DINNER_;   // Rc*512
  float* xc  = sz + (size_t)Rc * DINNER_;   // Rc*512
  float* dtT = xc + (size_t)Rc * DINNER_;   // Rc*512
  float* xcT = dtT + (size_t)Rc * DINNER_;  // Rc*512
  float* szT = xcT + (size_t)Rc * DINNER_;  // Rc*512 (y in place)
  float* Bm  = szT + (size_t)Rc * DINNER_;  // Rc*64
  float* Cm  = Bm + (size_t)Rc * DSTATE_;   // Rc*64
  float* xiC = Cm + (size_t)Rc * DSTATE_;   // 8*3*512
  float* hC  = xiC + BSZ_ * 3 * DINNER_;    // 8*512*64
  float* dtb = xi;

  for (int c = 0; c < nchunks; c++) {
    int n0 = c * L;
    int first = (c == 0) ? 1 : 0;
    ln_kernel<<<Rc / 4, 256, 0, stream>>>(x, ln_g, ln_b, xn, Rc, n0, lgL);
    gemm_kernel<1><<<dim3(1024 / 64, Rc / 64), 256, 0, stream>>>(xn, W_in, xi, sz, Rc, 1024, DIM_, 0, 0, 0);
    conv_silu_kernel<<<(Rc * DINNER_) / 256, 256, 0, stream>>>(xi, conv_w, conv_b, xc, xiC, Rc, first, lgL);
    save_carry_kernel<<<48, 256, 0, stream>>>(xi, xiC, L);
    xproj_kernel<<<Rc, 256, 0, stream>>>(xc, W_xp, W_dt, b_dt, dtb, Bm, Rc);
    cm_kernel<<<Rc / 4, 256, 0, stream>>>(C_SA, W_C, Cm, Rc, n0, lgL);
    transpose3_kernel<<<dim3(L / 64, DINNER_ / 64, 24), 256, 0, stream>>>(dtb, xc, sz, dtT, xcT, szT, L);
    scan_kernel<<<(BSZ_ * DINNER_) / 4, 256, 0, stream>>>(dtT, Bm, Cm, xcT, szT, A_log, Dp, hC, L, first);
    gemm_kernel<2><<<dim3(DIM_ / 64, Rc / 64), 256, 0, stream>>>(szT, W_out, out, nullptr, Rc, DIM_, DINNER_, n0, lgL, L);
  }
}